// Round 1
// 6375.174 us; speedup vs baseline: 2.5068x; 2.5068x over previous
//
#include <hip/hip_runtime.h>
#include <hip/hip_bf16.h>

typedef __hip_bfloat16 bf16;
typedef __attribute__((ext_vector_type(8))) short bf16x8;   // MFMA A/B frag (8 bf16)
typedef __attribute__((ext_vector_type(4))) short bf16x4;
typedef __attribute__((ext_vector_type(4))) float f32x4;    // MFMA C/D frag

__device__ __forceinline__ float ldE(const float* p) { return *p; }
__device__ __forceinline__ float ldE(const bf16* p)  { return (float)*p; }
__device__ __forceinline__ void stC(float* p, float v) { *p = v; }
__device__ __forceinline__ void stC(bf16* p, float v)  { *p = __float2bfloat16(v); }

__device__ __forceinline__ short f2s(float f) {
    bf16 b = __float2bfloat16(f);
    return __builtin_bit_cast(short, b);
}

// NaN-proof activations (clamp = no-op on sane data, sanitizes garbage).
__device__ __forceinline__ float sigm(float x) {
    x = fminf(fmaxf(x, -40.f), 40.f);
    return 1.f / (1.f + expf(-x));
}
__device__ __forceinline__ float tanh_s(float x) {
    x = fminf(fmaxf(x, -20.f), 20.f);
    float e = expf(2.f * x);
    return 1.f - 2.f / (e + 1.f);
}

// 16B-aligned 8-element loads -> bf16x8
__device__ __forceinline__ bf16x8 ld8(const bf16* p) {
    return *reinterpret_cast<const bf16x8*>(p);
}
__device__ __forceinline__ bf16x8 ld8(const float* p) {
    const float4 f0 = *reinterpret_cast<const float4*>(p);
    const float4 f1 = *reinterpret_cast<const float4*>(p + 4);
    bf16x8 v;
    v[0] = f2s(f0.x); v[1] = f2s(f0.y); v[2] = f2s(f0.z); v[3] = f2s(f0.w);
    v[4] = f2s(f1.x); v[5] = f2s(f1.y); v[6] = f2s(f1.z); v[7] = f2s(f1.w);
    return v;
}
// 8B-aligned 8-element load (rows with odd*8B stride)
__device__ __forceinline__ bf16x8 ld8_8B(const bf16* p) {
    bf16x4 lo = *reinterpret_cast<const bf16x4*>(p);
    bf16x4 hi = *reinterpret_cast<const bf16x4*>(p + 4);
    bf16x8 v;
    v[0] = lo[0]; v[1] = lo[1]; v[2] = lo[2]; v[3] = lo[3];
    v[4] = hi[0]; v[5] = hi[1]; v[6] = hi[2]; v[7] = hi[3];
    return v;
}

// f32 -> bf16 bulk convert
__global__ void f2b(const float* __restrict__ src, bf16* __restrict__ dst, long n) {
    long i = (long)blockIdx.x * 256 + threadIdx.x;
    if (i < n) dst[i] = __float2bfloat16(src[i]);
}

// ============================ MFMA GEMM ============================
// C[d] = A[d] (MxK row-major) @ W[d]^T (W is NcxK row-major f32, converted to
// bf16 in staging). BM=128 BN=64 BK=32, 256 thr = 4 waves, wave w owns rows
// [w*32, w*32+32): 2 m-frags x 4 n-frags of v_mfma_f32_16x16x32_bf16.
// VEC: fast staging path, requires K % 8 == 0 (and K % 4 == 0 for f32 A/W).
#define MBM 128
#define MBN 64
#define MLD 40   // padded LDS row stride in bf16 (80B): 2-way max on b128 frag reads

template <typename AT, typename CT, bool VEC>
__global__ __launch_bounds__(256) void gemm_mfma(
    const AT* __restrict__ A, long sAd,
    const float* __restrict__ W, long sWd,
    CT* __restrict__ C, long sCd,
    int M, int Nc, int K)
{
    __shared__ bf16 As[MBM * MLD];
    __shared__ bf16 Ws[MBN * MLD];
    const int d = blockIdx.z;
    A += (long)d * sAd; W += (long)d * sWd; C += (long)d * sCd;
    const int m0 = blockIdx.y * MBM;
    const int n0 = blockIdx.x * MBN;
    const int tid = threadIdx.x;
    const int w = tid >> 6, l = tid & 63;
    const int lr = l & 15, lq = l >> 4;

    f32x4 acc[2][4] = {};

    for (int k0 = 0; k0 < K; k0 += 32) {
        if (VEC) {
            // A: 128x32 = 512 8-elem units, 2/thread
#pragma unroll
            for (int i = 0; i < 2; ++i) {
                int u = tid + i * 256;
                int r = u >> 2, kk = (u & 3) * 8;
                bf16x8 v = {};
                if (m0 + r < M && k0 + kk < K)       // K%8==0: in -> all 8 in
                    v = ld8(A + (long)(m0 + r) * K + k0 + kk);
                *reinterpret_cast<bf16x8*>(&As[r * MLD + kk]) = v;
            }
            {   // W: 64x32 = 256 units, 1/thread
                int r = tid >> 2, kk = (tid & 3) * 8;
                bf16x8 v = {};
                if (n0 + r < Nc && k0 + kk < K)
                    v = ld8(W + (long)(n0 + r) * K + k0 + kk);
                *reinterpret_cast<bf16x8*>(&Ws[r * MLD + kk]) = v;
            }
        } else {
            // generic 2-elem units (handles any K, any row alignment)
#pragma unroll
            for (int i = 0; i < 8; ++i) {
                int u = tid + i * 256;
                int r = u >> 4, kk = (u & 15) * 2;
                float v0 = 0.f, v1 = 0.f;
                if (m0 + r < M) {
                    const AT* p = A + (long)(m0 + r) * K + k0 + kk;
                    if (k0 + kk < K)     v0 = ldE(p);
                    if (k0 + kk + 1 < K) v1 = ldE(p + 1);
                }
                As[r * MLD + kk]     = __float2bfloat16(v0);
                As[r * MLD + kk + 1] = __float2bfloat16(v1);
            }
#pragma unroll
            for (int i = 0; i < 4; ++i) {
                int u = tid + i * 256;
                int r = u >> 4, kk = (u & 15) * 2;
                float v0 = 0.f, v1 = 0.f;
                if (n0 + r < Nc) {
                    const float* p = W + (long)(n0 + r) * K + k0 + kk;
                    if (k0 + kk < K)     v0 = *p;
                    if (k0 + kk + 1 < K) v1 = *(p + 1);
                }
                Ws[r * MLD + kk]     = __float2bfloat16(v0);
                Ws[r * MLD + kk + 1] = __float2bfloat16(v1);
            }
        }
        __syncthreads();
        bf16x8 af[2], bw[4];
        af[0] = *reinterpret_cast<const bf16x8*>(&As[(w * 32 + lr) * MLD + lq * 8]);
        af[1] = *reinterpret_cast<const bf16x8*>(&As[(w * 32 + 16 + lr) * MLD + lq * 8]);
#pragma unroll
        for (int ni = 0; ni < 4; ++ni)
            bw[ni] = *reinterpret_cast<const bf16x8*>(&Ws[(ni * 16 + lr) * MLD + lq * 8]);
#pragma unroll
        for (int mi = 0; mi < 2; ++mi)
#pragma unroll
            for (int ni = 0; ni < 4; ++ni)
                acc[mi][ni] = __builtin_amdgcn_mfma_f32_16x16x32_bf16(
                    af[mi], bw[ni], acc[mi][ni], 0, 0, 0);
        __syncthreads();
    }
    // D layout: col = lane&15, row = (lane>>4)*4 + reg
#pragma unroll
    for (int mi = 0; mi < 2; ++mi) {
#pragma unroll
        for (int reg = 0; reg < 4; ++reg) {
            int m = m0 + w * 32 + mi * 16 + lq * 4 + reg;
            if (m >= M) continue;
#pragma unroll
            for (int ni = 0; ni < 4; ++ni) {
                int n = n0 + ni * 16 + lr;
                if (n < Nc) stC(&C[(long)m * Nc + n], acc[mi][ni][reg]);
            }
        }
    }
}

// ================== fused sentence GRU step (MFMA) ==================
// One kernel per time step: gh = h_bf[d] @ Whh_bf[d]^T for a 16-col j-tile
// (all 3 gate slices), gate math + h/h_bf/y update in the epilogue.
// Grid (44 j-tiles, 4 m-tiles of 32, 2 dirs), 128 thr = 2 waves;
// wave w owns batch rows mt*32 + w*16 + [0,16). Frags load direct from
// global (h_bf 0.36MB, Whh 5.9MB: L2-resident), 1-deep register prefetch.
// h_bf is ping-pong buffered: blocks read ping, write pong (no cross-block
// read/write race within a step); f32 master h is updated in place (a block
// only touches its own (m,j) elements).
__global__ __launch_bounds__(128) void gru_step_sent(
    const bf16* __restrict__ hr,     // read ping  [2,128,700]
    bf16* __restrict__ hw,           // write pong [2,128,700]
    const bf16* __restrict__ Whh,    // [2,2100,700] bf16
    const bf16* __restrict__ xw,     // [2,Cbuf,128,2100] bf16
    int tb0, int tb1, int Cbuf,
    const float* __restrict__ bih,   // [2,2100]
    const float* __restrict__ bhh,   // [2,2100]
    float* __restrict__ h,           // [2,128,700] f32 master
    bf16* __restrict__ y,            // [L,128,1400] or nullptr
    int L, int step)
{
    const int jt = blockIdx.x, mt = blockIdx.y, d = blockIdx.z;
    const int w = threadIdx.x >> 6, l = threadIdx.x & 63;
    const int lr = l & 15, lq = l >> 4;
    const int j0 = jt * 16;
    const int arow = mt * 32 + w * 16 + lr;              // A-frag batch row (<128)
    const bf16* Ab = hr + ((long)d * 128 + arow) * 700;
    const bf16* Wb = Whh + (long)d * 2100 * 700;
    const bool jok = (j0 + lr) < 700;
    const long wrow = (long)(j0 + lr) * 700;             // gate-0 row offset

    f32x4 acc[3] = {};

    auto lda = [&](int k0) -> bf16x8 {
        int kb = k0 + lq * 8;
        if (kb + 8 <= 700) return ld8_8B(Ab + kb);
        bf16x8 v = {};
#pragma unroll
        for (int i = 0; i < 8; ++i)
            if (kb + i < 700) v[i] = __builtin_bit_cast(short, Ab[kb + i]);
        return v;
    };
    auto ldb = [&](int g, int k0) -> bf16x8 {
        bf16x8 v = {};
        if (!jok) return v;
        const bf16* p = Wb + wrow + (long)g * 700 * 700;
        int kb = k0 + lq * 8;
        if (kb + 8 <= 700) return ld8_8B(p + kb);
#pragma unroll
        for (int i = 0; i < 8; ++i)
            if (kb + i < 700) v[i] = __builtin_bit_cast(short, p[kb + i]);
        return v;
    };

    bf16x8 a0 = lda(0), b0 = ldb(0, 0), b1 = ldb(1, 0), b2 = ldb(2, 0);
#pragma unroll 2
    for (int k0 = 0; k0 < 700; k0 += 32) {
        bf16x8 an, bn0, bn1, bn2;
        const bool more = (k0 + 32 < 700);
        if (more) {
            an = lda(k0 + 32);
            bn0 = ldb(0, k0 + 32); bn1 = ldb(1, k0 + 32); bn2 = ldb(2, k0 + 32);
        }
        acc[0] = __builtin_amdgcn_mfma_f32_16x16x32_bf16(a0, b0, acc[0], 0, 0, 0);
        acc[1] = __builtin_amdgcn_mfma_f32_16x16x32_bf16(a0, b1, acc[1], 0, 0, 0);
        acc[2] = __builtin_amdgcn_mfma_f32_16x16x32_bf16(a0, b2, acc[2], 0, 0, 0);
        if (more) { a0 = an; b0 = bn0; b1 = bn1; b2 = bn2; }
    }

    const int jcol = j0 + lr;
    if (jcol < 700) {
        const int t_eff = (d == 0) ? step : (L - 1 - step);
        const int tl = t_eff - ((d == 0) ? tb0 : tb1);
        const float bir = bih[d * 2100 + jcol];
        const float biz = bih[d * 2100 + 700 + jcol];
        const float bin = bih[d * 2100 + 1400 + jcol];
        const float bhr = bhh[d * 2100 + jcol];
        const float bhz = bhh[d * 2100 + 700 + jcol];
        const float bhn = bhh[d * 2100 + 1400 + jcol];
        const bf16* xbase = xw + (((long)d * Cbuf + tl) * 128) * 2100;
#pragma unroll
        for (int reg = 0; reg < 4; ++reg) {
            const int m = mt * 32 + w * 16 + lq * 4 + reg;     // D row = batch
            const bf16* xp = xbase + (long)m * 2100 + jcol;
            float r  = sigm((float)xp[0]    + bir + acc[0][reg] + bhr);
            float z  = sigm((float)xp[700]  + biz + acc[1][reg] + bhz);
            float nn = tanh_s((float)xp[1400] + bin + r * (acc[2][reg] + bhn));
            const long hidx = ((long)d * 128 + m) * 700 + jcol;
            const float hnew = (1.f - z) * nn + z * h[hidx];
            h[hidx] = hnew;
            hw[hidx] = __float2bfloat16(hnew);
            if (y) y[((long)t_eff * 128 + m) * 1400 + (long)d * 700 + jcol] =
                       __float2bfloat16(hnew);
        }
    }
}

// Word layer-0 GRU step: input gates gathered from embW[tok] (= emb @ Wih0^T).
__global__ void gru_step_word0(
    const int* __restrict__ x,      // [S,T,B]
    const bf16* __restrict__ embW,  // [2, V, 3H]
    const float* __restrict__ gh,   // [2, N, 3H]
    const float* __restrict__ bih,
    const float* __restrict__ bhh,
    float* __restrict__ h,          // [2, N, H]
    bf16* __restrict__ y,           // [T, N, 2H]
    int S, int T, int B, int V, int H, int k)
{
    const int N = S * B;
    long idx = (long)blockIdx.x * 256 + threadIdx.x;
    if (idx >= 2ll * N * H) return;
    int j = idx % H;
    int n = (idx / H) % N;
    int d = idx / ((long)N * H);
    int G = 3 * H;
    int t_eff = (d == 0) ? k : (T - 1 - k);
    int s = n / B, b = n % B;
    int tok = x[((long)s * T + t_eff) * B + b];
    tok = max(0, min(V - 1, tok));

    const bf16*  xp = embW + ((long)d * V + tok) * G;
    const float* gp = gh + ((long)d * N + n) * G;
    const float* bi = bih + (long)d * G;
    const float* bh = bhh + (long)d * G;

    float xr = (float)xp[j]         + bi[j];
    float xz = (float)xp[H + j]     + bi[H + j];
    float xn = (float)xp[2 * H + j] + bi[2 * H + j];
    float hr = gp[j]         + bh[j];
    float hz = gp[H + j]     + bh[H + j];
    float hn = gp[2 * H + j] + bh[2 * H + j];

    float r = sigm(xr + hr);
    float z = sigm(xz + hz);
    float nn = tanh_s(xn + r * hn);

    long hidx = ((long)d * N + n) * H + j;
    float hnew = (1.f - z) * nn + z * h[hidx];
    h[hidx] = hnew;
    y[((long)t_eff * N + n) * (2 * H) + (long)d * H + j] = __float2bfloat16(hnew);
}

// Generic GRU step (word layer 1). xw layout [2, Cbuf, N, 3H].
__global__ void gru_step1(
    const bf16* __restrict__ xw,
    int tb0, int tb1, int Cbuf,
    const float* __restrict__ gh,
    const float* __restrict__ bih,
    const float* __restrict__ bhh,
    float* __restrict__ h,
    bf16* __restrict__ y,
    int N, int H, int L, int k)
{
    long idx = (long)blockIdx.x * 256 + threadIdx.x;
    if (idx >= 2ll * N * H) return;
    int j = idx % H;
    int n = (idx / H) % N;
    int d = idx / ((long)N * H);
    int G = 3 * H;
    int t_eff = (d == 0) ? k : (L - 1 - k);
    int t_local = t_eff - ((d == 0) ? tb0 : tb1);

    const bf16*  xp = xw + (((long)d * Cbuf + t_local) * N + n) * G;
    const float* gp = gh + ((long)d * N + n) * G;
    const float* bi = bih + (long)d * G;
    const float* bh = bhh + (long)d * G;

    float xr = (float)xp[j]         + bi[j];
    float xz = (float)xp[H + j]     + bi[H + j];
    float xn = (float)xp[2 * H + j] + bi[2 * H + j];
    float hr = gp[j]         + bh[j];
    float hz = gp[H + j]     + bh[H + j];
    float hn = gp[2 * H + j] + bh[2 * H + j];

    float r = sigm(xr + hr);
    float z = sigm(xz + hz);
    float nn = tanh_s(xn + r * hn);

    long hidx = ((long)d * N + n) * H + j;
    float hnew = (1.f - z) * nn + z * h[hidx];
    h[hidx] = hnew;
    if (y) y[((long)t_eff * N + n) * (2 * H) + (long)d * H + j] = __float2bfloat16(hnew);
}

// out[n, 4H] = [ha_d0 | ha_d1 | hb_d0 | hb_d1]
template <typename OT>
__global__ void concat4(const float* __restrict__ ha, const float* __restrict__ hb,
                        OT* __restrict__ out, int N, int H)
{
    long idx = (long)blockIdx.x * 256 + threadIdx.x;
    int C4 = 4 * H;
    if (idx >= (long)N * C4) return;
    int c = idx % C4;
    long n = idx / C4;
    int blk = c / H, j = c % H;
    const float* src = (blk < 2) ? ha : hb;
    int dd = blk & 1;
    stC(&out[idx], src[((long)dd * N + n) * H + j]);
}

extern "C" void kernel_launch(void* const* d_in, const int* in_sizes, int n_in,
                              void* d_out, int out_size, void* d_ws, size_t ws_size,
                              hipStream_t stream)
{
    const int S = 120, T = 10, B = 128, E = 80, HW = 75, HS = 700, V = 30000;
    const int Nw = S * B;            // 15360
    const int Gw = 3 * HW;           // 225
    const int Gs = 3 * HS;           // 2100
    const int CH = 60;               // sentence chunk size
    (void)in_sizes; (void)n_in; (void)out_size; (void)ws_size;

    const int*   x       = (const int*)d_in[0];
    const float* emb     = (const float*)d_in[1];
    const float* we_Wih0 = (const float*)d_in[2],  *we_Whh0 = (const float*)d_in[3];
    const float* we_bih0 = (const float*)d_in[4],  *we_bhh0 = (const float*)d_in[5];
    const float* we_Wih1 = (const float*)d_in[6],  *we_Whh1 = (const float*)d_in[7];
    const float* we_bih1 = (const float*)d_in[8],  *we_bhh1 = (const float*)d_in[9];
    const float* se_Wih0 = (const float*)d_in[10], *se_Whh0 = (const float*)d_in[11];
    const float* se_bih0 = (const float*)d_in[12], *se_bhh0 = (const float*)d_in[13];
    const float* se_Wih1 = (const float*)d_in[14], *se_Whh1 = (const float*)d_in[15];
    const float* se_bih1 = (const float*)d_in[16], *se_bhh1 = (const float*)d_in[17];

    // ---- arenas (142.2 MB total; proven-safe < 149 MB) ----
    char* ws = (char*)d_ws;
    const size_t szA = 9216000;    // words bf16 [Nw,300]
    const size_t szB = 46080000;   // y0w bf16 [T*Nw,150] -> y0s bf16 [S*B,1400]=43.0MB
    const size_t szCDE = 68472000; // word: embW 27.0 | gh_w 27.648 | xw_w1 13.824
                                   // sent: xw_chunk bf16 [2,CH,B,Gs] = 64.512MB
    const size_t szF = 9216000;    // h_w0 -> Whh0_bf 5.88 | hbf0 pings 0.7168
    const size_t szG = 9216000;    // h_w1 -> h_s0|h_s1 1.4336 | Whh1_bf 5.88 | hbf1 0.7168
    char* pA = ws;
    char* pB = pA + szA;
    char* pC = pB + szB;
    char* pF = pC + szCDE;
    char* pG = pF + szF;
    const size_t total = szA + szB + szCDE + szF + szG;  // 142,200,000

    bf16*  words  = (bf16*)pA;
    bf16*  y0w    = (bf16*)pB;
    bf16*  y0s    = (bf16*)pB;
    bf16*  embW   = (bf16*)pC;                       // word phase
    float* gh_w   = (float*)(pC + 27000000);
    bf16*  xw_w1  = (bf16*)(pC + 27000000 + 27648000);
    bf16*  xw_ch  = (bf16*)pC;                       // sentence phase (overlays)
    float* h_w0   = (float*)pF;
    float* h_w1   = (float*)pG;
    // sentence-phase overlays (word buffers dead after concat4)
    bf16*  Whh0b  = (bf16*)pF;                       // [2,2100,700] bf16 = 5,880,000B
    bf16*  hbf0   = (bf16*)(pF + 5880000);           // 2 pings x [2,128,700] = 716,800B
    float* h_s0   = (float*)pG;                      // 716,800B
    float* h_s1   = (float*)(pG + 716800);           // 716,800B
    bf16*  Whh1b  = (bf16*)(pG + 1433600);           // 5,880,000B
    bf16*  hbf1   = (bf16*)(pG + 7313600);           // 716,800B
    const long HBP = 2L * 128 * 700;                 // ping stride (elems)

    hipMemsetAsync(ws, 0, total, stream);  // poison kill + h0 = 0

    // ===================== word encoder =====================
    // embW[d] = emb @ Wih0[d]^T : [V,80] @ [225,80]^T -> [2,V,225]  (K=80: VEC)
    gemm_mfma<float, bf16, true><<<dim3((Gw + MBN - 1) / MBN, (V + MBM - 1) / MBM, 2),
                                   256, 0, stream>>>(
        emb, 0, we_Wih0, (long)Gw * E, embW, (long)V * Gw, V, Gw, E);
    // ---- layer 0 ----
    for (int k = 0; k < T; ++k) {
        gemm_mfma<float, float, false><<<dim3((Gw + MBN - 1) / MBN, (Nw + MBM - 1) / MBM, 2),
                                         256, 0, stream>>>(
            h_w0, (long)Nw * HW, we_Whh0, (long)Gw * HW, gh_w, (long)Nw * Gw, Nw, Gw, HW);
        long tot = 2ll * Nw * HW;
        gru_step_word0<<<(tot + 255) / 256, 256, 0, stream>>>(
            x, embW, gh_w, we_bih0, we_bhh0, h_w0, y0w, S, T, B, V, HW, k);
    }
    // ---- layer 1 ----
    for (int k = 0; k < T; ++k) {
        gemm_mfma<bf16, bf16, false><<<dim3((Gw + MBN - 1) / MBN, (Nw + MBM - 1) / MBM, 2),
                                       256, 0, stream>>>(
            y0w + (long)k * Nw * 2 * HW, (long)(T - 1 - 2 * k) * Nw * 2 * HW,
            we_Wih1, (long)Gw * (2 * HW), xw_w1, (long)Nw * Gw, Nw, Gw, 2 * HW);
        gemm_mfma<float, float, false><<<dim3((Gw + MBN - 1) / MBN, (Nw + MBM - 1) / MBM, 2),
                                         256, 0, stream>>>(
            h_w1, (long)Nw * HW, we_Whh1, (long)Gw * HW, gh_w, (long)Nw * Gw, Nw, Gw, HW);
        long tot = 2ll * Nw * HW;
        gru_step1<<<(tot + 255) / 256, 256, 0, stream>>>(
            xw_w1, k, T - 1 - k, 1, gh_w, we_bih1, we_bhh1, h_w1, nullptr, Nw, HW, T, k);
    }
    {
        long tot = (long)Nw * 4 * HW;
        concat4<bf16><<<(tot + 255) / 256, 256, 0, stream>>>(h_w0, h_w1, words, Nw, HW);
    }

    // ===================== sentence encoder =====================
    // Whh -> bf16 (once); zero recurrent states (regions overlay word h's).
    {
        long nwh = 2LL * Gs * HS;  // 2,940,000
        f2b<<<(nwh + 255) / 256, 256, 0, stream>>>(se_Whh0, Whh0b, nwh);
        f2b<<<(nwh + 255) / 256, 256, 0, stream>>>(se_Whh1, Whh1b, nwh);
    }
    hipMemsetAsync(h_s0, 0, 2 * 716800, stream);   // h_s0 + h_s1
    hipMemsetAsync(hbf0, 0, 716800, stream);       // both pings
    hipMemsetAsync(hbf1, 0, 716800, stream);

    dim3 sgrid(44, 4, 2);   // 16-col j-tiles x 32-row m-tiles x dirs = 352 blocks

    // ---- layer 0: 2 chunks of 60 steps; xw batched per chunk (K=300) ----
    for (int c = 0; c < 2; ++c) {
        int tb0 = c * CH;
        int tb1 = S - c * CH - CH;
        gemm_mfma<bf16, bf16, false><<<dim3((Gs + MBN - 1) / MBN, (CH * B + MBM - 1) / MBM, 2),
                                       256, 0, stream>>>(
            words + (long)tb0 * B * (4 * HW), (long)(tb1 - tb0) * B * (4 * HW),
            se_Wih0, (long)Gs * (4 * HW), xw_ch, (long)CH * B * Gs, CH * B, Gs, 4 * HW);
        for (int k = c * CH; k < c * CH + CH; ++k) {
            int p = k & 1;
            gru_step_sent<<<sgrid, 128, 0, stream>>>(
                hbf0 + (long)p * HBP, hbf0 + (long)(p ^ 1) * HBP, Whh0b, xw_ch,
                tb0, tb1, CH, se_bih0, se_bhh0, h_s0, y0s, S, k);
        }
    }
    // ---- layer 1: same chunking; input = y0s (K=1400: VEC) ----
    for (int c = 0; c < 2; ++c) {
        int tb0 = c * CH;
        int tb1 = S - c * CH - CH;
        gemm_mfma<bf16, bf16, true><<<dim3((Gs + MBN - 1) / MBN, (CH * B + MBM - 1) / MBM, 2),
                                      256, 0, stream>>>(
            y0s + (long)tb0 * B * (2 * HS), (long)(tb1 - tb0) * B * (2 * HS),
            se_Wih1, (long)Gs * (2 * HS), xw_ch, (long)CH * B * Gs, CH * B, Gs, 2 * HS);
        for (int k = c * CH; k < c * CH + CH; ++k) {
            int p = k & 1;
            gru_step_sent<<<sgrid, 128, 0, stream>>>(
                hbf1 + (long)p * HBP, hbf1 + (long)(p ^ 1) * HBP, Whh1b, xw_ch,
                tb0, tb1, CH, se_bih1, se_bhh1, h_s1, nullptr, S, k);
        }
    }

    // out[1, B, 4*HS] = [sf0 | sb0 | sf1 | sb1]  (float32)
    {
        long tot = (long)B * 4 * HS;
        concat4<float><<<(tot + 255) / 256, 256, 0, stream>>>(h_s0, h_s1, (float*)d_out, B, HS);
    }
}